// Round 3
// baseline (293.303 us; speedup 1.0000x reference)
//
#include <hip/hip_runtime.h>

// shading(p) = n^T M n with n=(x,y,z,1), M symmetric from 9 SH coeffs.
// Expanded quadratic form: 10 per-batch wave-uniform scalars, ~10 FMA/pixel.
// Pure streaming: 201 MB read + 67 MB write -> ~40 us floor at measured
// 6.7 TB/s (harness fill BW). Bench dur_us also carries ~230 us of harness
// restore/poison cost (805 MB fills visible in rocprof) that is not ours.
//
// R3: fix R2 compile error — __builtin_nontemporal_store needs a NATIVE
// clang vector type, not HIP_vector_type<float,4>. Use ext_vector_type(4).

typedef float f32x4 __attribute__((ext_vector_type(4)));

#define V4_PER_THREAD 2   // float4 groups per thread per plane

__global__ __launch_bounds__(256) void shade_kernel(
    const float* __restrict__ light,     // [B,9]
    const float* __restrict__ normals,   // [B,3,W,H]
    float* __restrict__ out,             // [B,1,W,H]
    int WH)                              // W*H (512*512)
{
    const int b = blockIdx.y;
    const float* L = light + b * 9;

    const float C1 = 0.429043f, C2 = 0.511664f, C3 = 0.743152f,
                C4 = 0.886227f, C5 = 0.247708f;

    // wave-uniform (same b for whole block) -> scalar loads + broadcast
    const float L0 = L[0], L1 = L[1], L2 = L[2], L3 = L[3], L4 = L[4],
                L5 = L[5], L6 = L[6], L7 = L[7], L8 = L[8];

    const float axx =  C1 * L8;            // x^2
    const float ayy = -C1 * L8;            // y^2
    const float azz =  C3 * L6;            // z^2
    const float axy = 2.0f * C1 * L4;      // x*y
    const float axz = 2.0f * C1 * L7;      // x*z
    const float ayz = 2.0f * C1 * L5;      // y*z
    const float ax  = 2.0f * C2 * L3;      // x
    const float ay  = 2.0f * C2 * L1;      // y
    const float az  = 2.0f * C2 * L2;      // z
    const float a0  = C4 * L0 - C5 * L6;   // const

    const size_t base = (size_t)b * 3u * (size_t)WH;
    const float4* __restrict__ nx = (const float4*)(normals + base);
    const float4* __restrict__ ny = (const float4*)(normals + base + (size_t)WH);
    const float4* __restrict__ nz = (const float4*)(normals + base + 2u * (size_t)WH);
    f32x4* __restrict__ o = (f32x4*)(out + (size_t)b * (size_t)WH);

    const int i0 = (blockIdx.x * blockDim.x) * V4_PER_THREAD + threadIdx.x;

    float4 x[V4_PER_THREAD], y[V4_PER_THREAD], z[V4_PER_THREAD];
#pragma unroll
    for (int k = 0; k < V4_PER_THREAD; ++k) {
        const int i = i0 + k * 256;
        x[k] = nx[i];
        y[k] = ny[i];
        z[k] = nz[i];
    }

#pragma unroll
    for (int k = 0; k < V4_PER_THREAD; ++k) {
        f32x4 r;
#define SHADE(c, idx)                                                          \
        {                                                                      \
            const float xx = x[k].c, yy = y[k].c, zz = z[k].c;                 \
            float s = a0;                                                      \
            s = fmaf(xx, fmaf(axx, xx, fmaf(axy, yy, fmaf(axz, zz, ax))), s);  \
            s = fmaf(yy, fmaf(ayy, yy, fmaf(ayz, zz, ay)), s);                 \
            s = fmaf(zz, fmaf(azz, zz, az), s);                                \
            r[idx] = s;                                                        \
        }
        SHADE(x, 0); SHADE(y, 1); SHADE(z, 2); SHADE(w, 3);
#undef SHADE
        __builtin_nontemporal_store(r, &o[i0 + k * 256]);
    }
}

extern "C" void kernel_launch(void* const* d_in, const int* in_sizes, int n_in,
                              void* d_out, int out_size, void* d_ws, size_t ws_size,
                              hipStream_t stream) {
    const float* light   = (const float*)d_in[0];   // [B,9] fp32
    const float* normals = (const float*)d_in[1];   // [B,3,512,512] fp32
    float* out = (float*)d_out;                     // [B,1,512,512] fp32

    const int B  = in_sizes[0] / 9;                 // 64
    const int WH = in_sizes[1] / (B * 3);           // 262144

    const int threads = 256;
    const int v4_per_batch = WH / 4;                          // 65536
    dim3 grid(v4_per_batch / (threads * V4_PER_THREAD), B);   // (128, 64)

    shade_kernel<<<grid, dim3(threads), 0, stream>>>(light, normals, out, WH);
}